// Round 11
// baseline (134.387 us; speedup 1.0000x reference)
//
#include <hip/hip_runtime.h>

#define EG   16000   // graph edges
#define NG   1000    // graph_size (block rows/cols)
#define BB   32      // batch
#define SIZE 16000   // feature length (NG*16)
#define CAP  64      // per-bin capacity (Poisson(16): P(>64) ~ 1e-18)

typedef float f32x4 __attribute__((ext_vector_type(4)));

// ---- kernel 1: gather strided edge headers into dense pk[e]=(t0<<10)|t1 ----
// Writes every entry each launch: ws poison is never read. No memset needed.
__global__ __launch_bounds__(256) void pack_kernel(
    const int* __restrict__ rows, const int* __restrict__ cols,
    int* __restrict__ pk)
{
    int e = blockIdx.x * 256 + threadIdx.x;
    if (e < EG) {
        int t0 = rows[(long)e << 8] >> 4;   // rows[e*256] = t0*16
        int t1 = cols[(long)e << 8] >> 4;   // cols[e*256] = t1*16
        pk[e] = (t0 << 10) | t1;            // 20 bits
    }
}

// ---- kernel 2: batch-split spmm. 2000 blocks = 1000 bins x 2 batch-halves ----
// Block (g, half) computes out[half*16+0..15, g*16+0..15]: exclusive stores,
// no atomics, bias fused. 18.7KB LDS -> 8 blocks/CU (32 waves, 100% occ);
// 2000 blocks give scheduler backfill against Poisson(16) bin imbalance.
// Pairing: pair blocks (bid, bid+1000) share g; 1000 % 8 == 0 -> same XCD ->
// the pair's duplicate w-stream read is an L2 hit, not HBM.
// NOTE (r8/r9): no in-kernel grid barriers (coop launch breaks graph capture;
// spin barriers cost ~130us). Dispatch boundary = cheapest grid barrier.
// NOTE (r3): keep stores/atomics line-clustered and wave-private.
__global__ __launch_bounds__(256, 8) void spmm_kernel(
    const float* __restrict__ wm, const float* __restrict__ wlv,
    const float* __restrict__ ew, const float* __restrict__ x,
    const float* __restrict__ bm, const float* __restrict__ blv,
    const float* __restrict__ eb, const int* __restrict__ pk,
    float* __restrict__ out)
{
    __shared__ f32x4 vt[2][4][64];    // [buf][slot][i*4+jg] sampled weights (8KB)
    __shared__ f32x4 xs[2][4][80];    // [buf][slot][lb*5+q] x rows, pad-5 (10KB)
    __shared__ int   sl[CAP];         // packed (e<<10)|t1 for this bin
    __shared__ int   scnt;

    int bid  = blockIdx.x;
    int half = bid / 1000;            // batch half: rows [half*16, half*16+16)
    int g    = bid - half * 1000;     // bin (pair distance 1000 = 0 mod 8: same XCD)
    int tid  = threadIdx.x;
    int bb0  = half << 4;

    // ---- phase 1: scan dense pk, compact own edges ----
    if (tid == 0) scnt = 0;
    __syncthreads();
    const int4* pk4 = (const int4*)pk;
    for (int c = tid; c < EG / 4; c += 256) {      // 16 coalesced L2 iterations
        int4 v = pk4[c];
        int e0 = c << 2;
        if ((v.x >> 10) == g) { int p = atomicAdd(&scnt, 1); if (p < CAP) sl[p] = ((e0    ) << 10) | (v.x & 1023); }
        if ((v.y >> 10) == g) { int p = atomicAdd(&scnt, 1); if (p < CAP) sl[p] = ((e0 + 1) << 10) | (v.y & 1023); }
        if ((v.z >> 10) == g) { int p = atomicAdd(&scnt, 1); if (p < CAP) sl[p] = ((e0 + 2) << 10) | (v.z & 1023); }
        if ((v.w >> 10) == g) { int p = atomicAdd(&scnt, 1); if (p < CAP) sl[p] = ((e0 + 3) << 10) | (v.w & 1023); }
    }
    __syncthreads();
    int n = scnt; n = n < CAP ? n : CAP;

    // ---- phase 2: spmm over own batch half ----
    int wave = tid >> 6;              // edge slot 0..3
    int lane = tid & 63;
    int jg   = lane & 3;              // col group (4 cols)
    int cb   = lane >> 2;             // local batch 0..15

    f32x4 acc = {0.f, 0.f, 0.f, 0.f};
    f32x4 m4, l4, g4, xv0;            // staged regs (in flight across compute)
    int iters = (n + 3) >> 2;
    bool vcur = false, vnxt = false;

    auto issue = [&](int idx) -> bool {     // global loads only (no LDS writes)
        bool val = idx < n;
        if (val) {                          // wave-uniform branch
            int pkv = sl[idx];
            int e   = pkv >> 10;
            int t1  = pkv & 1023;
            long wq = ((long)e << 6) + lane;
            m4 = ((const f32x4*)wm)[wq];    // 3 x b128, coalesced 1KB/wave
            l4 = ((const f32x4*)wlv)[wq];
            g4 = ((const f32x4*)ew)[wq];
            const f32x4* x4 = (const f32x4*)x;
            int lb = lane >> 2, q = lane & 3;      // 16 rows x 4 chunks
            xv0 = x4[(long)(bb0 + lb) * (SIZE/4) + (t1 << 2) + q];
        }
        return val;
    };
    auto writeb = [&](int buf, bool val) {  // vmcnt wait lands here (T14)
        if (val) {
            f32x4 v;
            v.x = g4.x * __expf(l4.x) + m4.x;
            v.y = g4.y * __expf(l4.y) + m4.y;
            v.z = g4.z * __expf(l4.z) + m4.z;
            v.w = g4.w * __expf(l4.w) + m4.w;
            vt[buf][wave][lane] = v;        // chunk lane = (i=lane>>2, jg=lane&3)
            int lb = lane >> 2, q = lane & 3;
            xs[buf][wave][lb * 5 + q] = xv0;
        }
    };
    auto compute = [&](int buf, bool val) {
        if (!val) return;                   // wave-uniform
        f32x4 x0 = xs[buf][wave][cb * 5 + 0];   // own batch row (broadcast quads,
        f32x4 x1 = xs[buf][wave][cb * 5 + 1];   //  pad-5: cb vs cb+8 2-way = free)
        f32x4 x2 = xs[buf][wave][cb * 5 + 2];
        f32x4 x3 = xs[buf][wave][cb * 5 + 3];
        float xr[16] = {x0.x,x0.y,x0.z,x0.w, x1.x,x1.y,x1.z,x1.w,
                        x2.x,x2.y,x2.z,x2.w, x3.x,x3.y,x3.z,x3.w};
        #pragma unroll
        for (int i = 0; i < 16; ++i) {
            f32x4 w = vt[buf][wave][(i << 2) + jg];  // 16-lane broadcast chunks
            acc += w * xr[i];               // 4 FMA (static index after unroll)
        }
    };

    // prologue
    vcur = issue(wave);
    writeb(0, vcur);
    __syncthreads();
    // main loop: one barrier per 4-edge iteration
    for (int it = 0; it < iters; ++it) {
        bool more = (it + 1 < iters);
        if (more) vnxt = issue(((it + 1) << 2) + wave);  // globals in flight
        compute(it & 1, vcur);                            // LDS+VALU overlap
        if (more) writeb((it + 1) & 1, vnxt);
        __syncthreads();
        vcur = vnxt;
    }

    // ---- epilogue: cross-slot reduce + fused bias + exclusive store ----
    f32x4* sred = &xs[0][0][0];            // overlay: xs dead after last barrier
    sred[(wave << 6) + lane] = acc;        // 4KB
    __syncthreads();
    if (tid < 64) {
        int cbf = tid >> 2;                // local batch 0..15
        int jgf = tid & 3;
        f32x4 s = sred[(0 << 6) + tid] + sred[(1 << 6) + tid]
                + sred[(2 << 6) + tid] + sred[(3 << 6) + tid];
        int r0 = (g << 4) + (jgf << 2);    // 16B-aligned
        f32x4 b4 = *(const f32x4*)&bm[r0];
        f32x4 v4 = *(const f32x4*)&blv[r0];
        f32x4 e4 = *(const f32x4*)&eb[r0];
        f32x4 o;
        o.x = s.x + (e4.x * __expf(v4.x) + b4.x);
        o.y = s.y + (e4.y * __expf(v4.y) + b4.y);
        o.z = s.z + (e4.z * __expf(v4.z) + b4.z);
        o.w = s.w + (e4.w * __expf(v4.w) + b4.w);
        *(f32x4*)&out[(long)(bb0 + cbf) * SIZE + r0] = o;
    }
    if (bid == 0 && tid == 0) out[(long)BB * SIZE] = 0.0f;   // kl scalar
}

extern "C" void kernel_launch(void* const* d_in, const int* in_sizes, int n_in,
                              void* d_out, int out_size, void* d_ws, size_t ws_size,
                              hipStream_t stream) {
    const float* x   = (const float*)d_in[0];
    const float* wm  = (const float*)d_in[1];
    const float* wlv = (const float*)d_in[2];
    const float* bm  = (const float*)d_in[3];
    const float* blv = (const float*)d_in[4];
    const float* ew  = (const float*)d_in[5];
    const float* eb  = (const float*)d_in[6];
    const int* rows  = (const int*)d_in[7];
    const int* cols  = (const int*)d_in[8];
    float* out = (float*)d_out;

    int* pk = (int*)d_ws;                 // 16000 ints = 64KB dense edge headers

    pack_kernel<<<(EG + 255) / 256, 256, 0, stream>>>(rows, cols, pk);
    spmm_kernel<<<2 * NG, 256, 0, stream>>>(wm, wlv, ew, x, bm, blv, eb, pk, out);
}